// Round 13
// baseline (327.339 us; speedup 1.0000x reference)
//
#include <hip/hip_runtime.h>
#include <hip/hip_fp16.h>

// ---------------------------------------------------------------------------
// RelGraphConv (basis-decomposed, right-norm, sum over relations) on MI355X.
//
//   h[d] = B0^T * A0[d] + B1^T * A1[d] + x[d]@Wl + bias,  ReLU
//   A_b[d] = sum_{edges e->d} (coeff[r_e][b]/deg[r_e][d]) * x[src_e]
// R13: gather and final GEMM FUSED. Block = 64 dst nodes: phase 1 gathers
// agg rows into LDS (64x256 bf16, 34KB — aggb never exists in HBM: saves
// 51MB write + 51MB read), one barrier, phase 2 MFMAs [LDS|xb] @ w2T -> out.
// Standalone GEMM was stuck >=60us across 3 structures (staged/global-B/
// streaming): ~128MB moved at 2-3 blk/CU never hides latency. R12 lesson:
// compiler defeats source-level load batching (VGPR stayed 48).
// ---------------------------------------------------------------------------

#define DFEAT 128
#define NREL 8
#define ALDA 264   // LDS agg row stride in ushorts (256 data + 8 pad)

typedef __attribute__((ext_vector_type(8))) short bf16x8;
typedef __attribute__((ext_vector_type(4))) float f32x4;
typedef __attribute__((ext_vector_type(2))) float f32x2;

__device__ __forceinline__ ushort f2bf(float f) {
    unsigned u = __float_as_uint(f);
    u += 0x7FFF + ((u >> 16) & 1);          // round-to-nearest-even
    return (ushort)(u >> 16);
}
__device__ __forceinline__ float bflo(unsigned u) { return __uint_as_float(u << 16); }
__device__ __forceinline__ float bfhi(unsigned u) { return __uint_as_float(u & 0xFFFF0000u); }

// Fused: count_rank (atomic-latency-bound) + convert_x + build_w2T (BW-bound).
// deg must be pre-zeroed. w2T[j][k]: k<256 -> bases[k>>7][k&127][j],
// else loopw[k-256][j].
__global__ void fused_pre(const int* __restrict__ dst, int* __restrict__ deg,
                          ushort* __restrict__ rank,
                          const float* __restrict__ x, ushort* __restrict__ xb,
                          const float* __restrict__ bases, const float* __restrict__ loopw,
                          ushort* __restrict__ w2T,
                          int RE, int E, int N, int n4) {
    const int stride = gridDim.x * blockDim.x;
    const int t0 = blockIdx.x * blockDim.x + threadIdx.x;
    for (int i = t0; i < RE; i += stride) {
        int r = i / E;
        int d = dst[i];
        rank[i] = (ushort)atomicAdd(&deg[r * N + d], 1);
    }
    for (int i = t0; i < n4; i += stride) {
        float4 v = ((const float4*)x)[i];
        ushort4 o;
        o.x = f2bf(v.x); o.y = f2bf(v.y); o.z = f2bf(v.z); o.w = f2bf(v.w);
        ((ushort4*)xb)[i] = o;
    }
    for (int i = t0; i < 128 * 384; i += stride) {
        int j = i / 384, k = i % 384;
        float v = (k < 256) ? bases[(k >> 7) * DFEAT * DFEAT + (k & 127) * DFEAT + j]
                            : loopw[(k - 256) * DFEAT + j];
        w2T[i] = f2bf(v);
    }
}

// Per 1024-node chunk: cnt[d] = sum_r deg[r][d]; bsums[b] = chunk total.
__global__ void scan_block_sums(const int* __restrict__ deg, int* __restrict__ cnt,
                                int* __restrict__ bsums, int N) {
    __shared__ int sdata[256];
    int b = blockIdx.x, t = threadIdx.x;
    int sum = 0;
    for (int j = 0; j < 4; ++j) {
        int idx = b * 1024 + j * 256 + t;
        if (idx < N) {
            int tot = 0;
            #pragma unroll
            for (int r = 0; r < NREL; ++r) tot += deg[r * N + idx];
            cnt[idx] = tot;
            sum += tot;
        }
    }
    sdata[t] = sum; __syncthreads();
    for (int s = 128; s > 0; s >>= 1) {
        if (t < s) sdata[t] += sdata[t + s];
        __syncthreads();
    }
    if (t == 0) bsums[b] = sdata[0];
}

// single-block exclusive scan of bsums[nb], nb <= 1024
__global__ void scan_mid(int* __restrict__ bsums, int nb) {
    __shared__ int s[256];
    int t = threadIdx.x;
    int base = t * 4;
    int v[4]; int sum = 0;
    #pragma unroll
    for (int i = 0; i < 4; ++i) {
        v[i] = sum;
        int c = (base + i < nb) ? bsums[base + i] : 0;
        sum += c;
    }
    s[t] = sum; __syncthreads();
    for (int off = 1; off < 256; off <<= 1) {
        int add = (t >= off) ? s[t - off] : 0;
        __syncthreads();
        s[t] += add;
        __syncthreads();
    }
    int excl = (t == 0) ? 0 : s[t - 1];
    #pragma unroll
    for (int i = 0; i < 4; ++i)
        if (base + i < nb) bsums[base + i] = excl + v[i];
}

// rowStart[d] + packed[r*N+d] = ((rowStart[d]+prefix_r)<<11)|deg_rd
__global__ void scan_write(const int* __restrict__ cnt, const int* __restrict__ bsums,
                           const int* __restrict__ deg,
                           int* __restrict__ rowStart, unsigned* __restrict__ packed,
                           int N) {
    __shared__ int tsum[256];
    int b = blockIdx.x, t = threadIdx.x;
    int base = b * 1024 + t * 4;
    int v[4];
    int s = 0;
    #pragma unroll
    for (int i = 0; i < 4; ++i) {
        int idx = base + i;
        v[i] = s;
        int c = (idx < N) ? cnt[idx] : 0;
        s += c;
    }
    tsum[t] = s; __syncthreads();
    for (int off = 1; off < 256; off <<= 1) {
        int x = 0;
        if (t >= off) x = tsum[t - off];
        __syncthreads();
        if (t >= off) tsum[t] += x;
        __syncthreads();
    }
    int excl = (t == 0) ? 0 : tsum[t - 1];
    int boff = bsums[b];
    #pragma unroll
    for (int i = 0; i < 4; ++i) {
        int idx = base + i;
        if (idx < N) {
            int rs = boff + excl + v[i];
            rowStart[idx] = rs;
            int pre = 0;
            #pragma unroll
            for (int r = 0; r < NREL; ++r) {
                int dv = deg[r * N + idx];
                packed[r * N + idx] = ((unsigned)(rs + pre) << 11) | (unsigned)dv;
                pre += dv;
            }
        }
    }
}

// Atomic-free placement: pos = (packed>>11) + rank. ONE random read per edge.
__global__ void fill_kernel(const int* __restrict__ src, const int* __restrict__ dst,
                            const float* __restrict__ coeff,
                            const ushort* __restrict__ rank,
                            const unsigned* __restrict__ packed,
                            uint2* __restrict__ recs, int RE, int E, int N) {
    int idx = blockIdx.x * blockDim.x + threadIdx.x;
    if (idx >= RE) return;
    int r = idx / E;
    int d = dst[idx];
    unsigned p = packed[r * N + d];
    int pos = (int)(p >> 11) + (int)rank[idx];
    float inv = 1.0f / (float)(p & 2047u);
    __half2 hc = __floats2half2_rn(coeff[2 * r] * inv, coeff[2 * r + 1] * inv);
    uint2 rec;
    rec.x = (unsigned)src[idx];
    rec.y = *(unsigned*)&hc;
    recs[pos] = rec;
}

// ---------------------------------------------------------------------------
// FUSED gather + GEMM. Block = 64 dst nodes (row0..row0+63).
// Phase 1: wave w gathers nodes {w, w+4, ...} (16 each) into LDS agg rows
//   (half-wave per edge, 4-pair unroll, f32x2 pk-fma; half0 -> A0 128 feats,
//   half1 -> A1 128 feats; row = 256 bf16).
// Phase 2: out[64,128] = relu([aggLDS|xb][64,384] @ w2T^T + bias).
//   A frags: kt 0,1 from LDS; kt 2 from xb (global). B frags: regs from
//   L2-hot w2T. Epilogue C layout: col=l16+16g+32w, row=m*16+quad*4+reg.
// ---------------------------------------------------------------------------
__global__ __launch_bounds__(256, 4) void gather_gemm(
    const uint2* __restrict__ recs, const int* __restrict__ rowStart,
    const int* __restrict__ cnt, const ushort* __restrict__ xb,
    const ushort* __restrict__ w2T, const float* __restrict__ bias,
    float* __restrict__ out, int N) {
    __shared__ __align__(16) ushort agg[64 * ALDA];   // 33.8 KB
    const int tid = threadIdx.x;
    const int wave = tid >> 6, lane = tid & 63;
    const int half = lane >> 5;
    const int h = lane & 31;
    const int row0 = blockIdx.x * 64;

    // ---- phase 1: gather ----
    for (int i = wave; i < 64; i += 4) {
        int d = row0 + i;
        if (d >= N) break;
        f32x2 A0 = {0.f, 0.f}, A1 = {0.f, 0.f};   // c0 side
        f32x2 B0 = {0.f, 0.f}, B1 = {0.f, 0.f};   // c1 side
        const int start = rowStart[d];
        const int len = cnt[d];
        int i2 = 0;
        for (; i2 + 8 <= len; i2 += 8) {
            uint2 r0 = recs[start + i2 + half];
            uint2 r1 = recs[start + i2 + 2 + half];
            uint2 r2 = recs[start + i2 + 4 + half];
            uint2 r3 = recs[start + i2 + 6 + half];
            uint2 u0 = *(const uint2*)(xb + (size_t)r0.x * DFEAT + h * 4);
            uint2 u1 = *(const uint2*)(xb + (size_t)r1.x * DFEAT + h * 4);
            uint2 u2 = *(const uint2*)(xb + (size_t)r2.x * DFEAT + h * 4);
            uint2 u3 = *(const uint2*)(xb + (size_t)r3.x * DFEAT + h * 4);
            #pragma unroll
            for (int q = 0; q < 4; ++q) {
                uint2 rr = q == 0 ? r0 : q == 1 ? r1 : q == 2 ? r2 : r3;
                uint2 uu = q == 0 ? u0 : q == 1 ? u1 : q == 2 ? u2 : u3;
                __half2 hc = *(__half2*)&rr.y;
                float c0 = __low2float(hc), c1 = __high2float(hc);
                f32x2 cc0 = {c0, c0}, cc1 = {c1, c1};
                f32x2 f01 = {bflo(uu.x), bfhi(uu.x)};
                f32x2 f23 = {bflo(uu.y), bfhi(uu.y)};
                A0 += cc0 * f01; A1 += cc0 * f23;
                B0 += cc1 * f01; B1 += cc1 * f23;
            }
        }
        for (; i2 < len; i2 += 2) {
            int e = i2 + half;
            bool valid = e < len;
            uint2 rr = recs[start + (valid ? e : i2)];
            __half2 hc = *(__half2*)&rr.y;
            float c0 = valid ? __low2float(hc) : 0.f;
            float c1 = valid ? __high2float(hc) : 0.f;
            uint2 uu = *(const uint2*)(xb + (size_t)rr.x * DFEAT + h * 4);
            f32x2 cc0 = {c0, c0}, cc1 = {c1, c1};
            f32x2 f01 = {bflo(uu.x), bfhi(uu.x)};
            f32x2 f23 = {bflo(uu.y), bfhi(uu.y)};
            A0 += cc0 * f01; A1 += cc0 * f23;
            B0 += cc1 * f01; B1 += cc1 * f23;
        }
        A0.x += __shfl_xor(A0.x, 32); A0.y += __shfl_xor(A0.y, 32);
        A1.x += __shfl_xor(A1.x, 32); A1.y += __shfl_xor(A1.y, 32);
        B0.x += __shfl_xor(B0.x, 32); B0.y += __shfl_xor(B0.y, 32);
        B1.x += __shfl_xor(B1.x, 32); B1.y += __shfl_xor(B1.y, 32);
        f32x2 O01 = half ? B0 : A0;
        f32x2 O23 = half ? B1 : A1;
        ushort4 o = make_ushort4(f2bf(O01.x), f2bf(O01.y), f2bf(O23.x), f2bf(O23.y));
        *(ushort4*)(agg + i * ALDA + lane * 4) = o;
    }
    __syncthreads();

    // ---- phase 2: GEMM ----
    const int quad = lane >> 4, l16 = lane & 15;
    int arow[4];
    #pragma unroll
    for (int m = 0; m < 4; ++m) {
        int r = row0 + m * 16 + l16;
        arow[m] = (r < N) ? r : 0;
    }

    f32x4 zero = {0.f, 0.f, 0.f, 0.f};
    f32x4 acc[4][2] = {{zero, zero}, {zero, zero}, {zero, zero}, {zero, zero}};

    #pragma unroll
    for (int kt = 0; kt < 3; ++kt) {
        bf16x8 bq[4][2];
        #pragma unroll
        for (int t = 0; t < 4; ++t)
            #pragma unroll
            for (int g = 0; g < 2; ++g)
                bq[t][g] = *(const bf16x8*)(w2T + (size_t)(wave * 32 + g * 16 + l16) * 384
                                            + kt * 128 + t * 32 + quad * 8);
        #pragma unroll
        for (int m = 0; m < 4; ++m) {
            #pragma unroll
            for (int t = 0; t < 4; ++t) {
                bf16x8 a;
                if (kt < 2)
                    a = *(const bf16x8*)(agg + (m * 16 + l16) * ALDA + kt * 128 + t * 32 + quad * 8);
                else
                    a = *(const bf16x8*)(xb + (size_t)arow[m] * DFEAT + t * 32 + quad * 8);
                acc[m][0] = __builtin_amdgcn_mfma_f32_16x16x32_bf16(a, bq[t][0], acc[m][0], 0, 0, 0);
                acc[m][1] = __builtin_amdgcn_mfma_f32_16x16x32_bf16(a, bq[t][1], acc[m][1], 0, 0, 0);
            }
        }
    }

    #pragma unroll
    for (int g = 0; g < 2; ++g) {
        int c = wave * 32 + g * 16 + l16;
        float bv = bias[c];
        #pragma unroll
        for (int m = 0; m < 4; ++m) {
            #pragma unroll
            for (int reg = 0; reg < 4; ++reg) {
                int grow = row0 + m * 16 + quad * 4 + reg;
                if (grow < N)
                    out[(size_t)grow * DFEAT + c] = fmaxf(acc[m][g][reg] + bv, 0.f);
            }
        }
    }
}

extern "C" void kernel_launch(void* const* d_in, const int* in_sizes, int n_in,
                              void* d_out, int out_size, void* d_ws, size_t ws_size,
                              hipStream_t stream) {
    const float* x     = (const float*)d_in[0];
    const int*   src   = (const int*)  d_in[1];
    const int*   dst   = (const int*)  d_in[2];
    const float* coeff = (const float*)d_in[3];
    const float* bases = (const float*)d_in[4];
    const float* loopw = (const float*)d_in[5];
    const float* bias  = (const float*)d_in[6];
    float* out = (float*)d_out;

    const int N  = in_sizes[0] / DFEAT;            // 100000
    const int RE = in_sizes[1];                    // R*E = 1200000
    const int B  = in_sizes[4] / (DFEAT * DFEAT);  // 2
    const int R  = in_sizes[3] / B;                // 8
    const int E  = RE / R;                         // 150000
    const int NB = (N + 1023) / 1024;              // scan blocks

    // workspace layout
    char* ws = (char*)d_ws;
    size_t off = 0;
    auto alloc = [&](size_t bytes) { void* p = ws + off; off = (off + bytes + 255) & ~(size_t)255; return p; };
    int*      deg      = (int*)     alloc((size_t)R * N * sizeof(int));     // 3.2 MB
    ushort*   rank     = (ushort*)  alloc((size_t)RE * sizeof(ushort));     // 2.4 MB
    unsigned* packed   = (unsigned*)alloc((size_t)R * N * sizeof(unsigned));// 3.2 MB
    int*      cnt      = (int*)     alloc((size_t)N * sizeof(int));
    int*      rowStart = (int*)     alloc((size_t)N * sizeof(int));
    int*      bsums    = (int*)     alloc((size_t)NB * sizeof(int));
    ushort*   w2T      = (ushort*)  alloc((size_t)128 * 384 * sizeof(ushort));
    ushort*   xb       = (ushort*)  alloc((size_t)N * DFEAT * sizeof(ushort)); // 25.6 MB
    uint2*    recs     = (uint2*)   alloc((size_t)RE * sizeof(uint2));         // 9.6 MB

    hipMemsetAsync(deg, 0, (size_t)R * N * sizeof(int), stream);
    fused_pre<<<4096, 256, 0, stream>>>(dst, deg, rank, x, xb, bases, loopw, w2T,
                                        RE, E, N, N * 32);
    scan_block_sums<<<NB, 256, 0, stream>>>(deg, cnt, bsums, N);
    scan_mid<<<1, 256, 0, stream>>>(bsums, NB);
    scan_write<<<NB, 256, 0, stream>>>(cnt, bsums, deg, rowStart, packed, N);
    fill_kernel<<<(RE + 255) / 256, 256, 0, stream>>>(src, dst, coeff, rank, packed,
                                                      recs, RE, E, N);

    gather_gemm<<<(N + 63) / 64, 256, 0, stream>>>(recs, rowStart, cnt, xb, w2T,
                                                   bias, out, N);
}

// Round 14
// 302.733 us; speedup vs baseline: 1.0813x; 1.0813x over previous
//
#include <hip/hip_runtime.h>
#include <hip/hip_fp16.h>

// ---------------------------------------------------------------------------
// RelGraphConv (basis-decomposed, right-norm, sum over relations) on MI355X.
//
//   h[d] = B0^T * A0[d] + B1^T * A1[d] + x[d]@Wl + bias,  ReLU
//   A_b[d] = sum_{edges e->d} (coeff[r_e][b]/deg[r_e][d]) * x[src_e]
// R14: fused gather+GEMM kept, but 32-row tiles (LDS 16.9KB, launch_bounds
// (256,6) -> 24 waves/CU) — R13's 64-row/34KB version halved the gather
// phase's occupancy (32% vs 67% standalone) and ran 139us despite saving
// 100MB of HBM traffic. Occupancy IS the gather's latency hiding.
// ---------------------------------------------------------------------------

#define DFEAT 128
#define NREL 8
#define ALDA 264   // LDS agg row stride in ushorts (256 data + 8 pad)

typedef __attribute__((ext_vector_type(8))) short bf16x8;
typedef __attribute__((ext_vector_type(4))) float f32x4;
typedef __attribute__((ext_vector_type(2))) float f32x2;

__device__ __forceinline__ ushort f2bf(float f) {
    unsigned u = __float_as_uint(f);
    u += 0x7FFF + ((u >> 16) & 1);          // round-to-nearest-even
    return (ushort)(u >> 16);
}
__device__ __forceinline__ float bflo(unsigned u) { return __uint_as_float(u << 16); }
__device__ __forceinline__ float bfhi(unsigned u) { return __uint_as_float(u & 0xFFFF0000u); }

// Fused: count_rank (atomic-latency-bound) + convert_x + build_w2T (BW-bound).
// deg must be pre-zeroed. w2T[j][k]: k<256 -> bases[k>>7][k&127][j],
// else loopw[k-256][j].
__global__ void fused_pre(const int* __restrict__ dst, int* __restrict__ deg,
                          ushort* __restrict__ rank,
                          const float* __restrict__ x, ushort* __restrict__ xb,
                          const float* __restrict__ bases, const float* __restrict__ loopw,
                          ushort* __restrict__ w2T,
                          int RE, int E, int N, int n4) {
    const int stride = gridDim.x * blockDim.x;
    const int t0 = blockIdx.x * blockDim.x + threadIdx.x;
    for (int i = t0; i < RE; i += stride) {
        int r = i / E;
        int d = dst[i];
        rank[i] = (ushort)atomicAdd(&deg[r * N + d], 1);
    }
    for (int i = t0; i < n4; i += stride) {
        float4 v = ((const float4*)x)[i];
        ushort4 o;
        o.x = f2bf(v.x); o.y = f2bf(v.y); o.z = f2bf(v.z); o.w = f2bf(v.w);
        ((ushort4*)xb)[i] = o;
    }
    for (int i = t0; i < 128 * 384; i += stride) {
        int j = i / 384, k = i % 384;
        float v = (k < 256) ? bases[(k >> 7) * DFEAT * DFEAT + (k & 127) * DFEAT + j]
                            : loopw[(k - 256) * DFEAT + j];
        w2T[i] = f2bf(v);
    }
}

// Per 1024-node chunk: cnt[d] = sum_r deg[r][d]; bsums[b] = chunk total.
__global__ void scan_block_sums(const int* __restrict__ deg, int* __restrict__ cnt,
                                int* __restrict__ bsums, int N) {
    __shared__ int sdata[256];
    int b = blockIdx.x, t = threadIdx.x;
    int sum = 0;
    for (int j = 0; j < 4; ++j) {
        int idx = b * 1024 + j * 256 + t;
        if (idx < N) {
            int tot = 0;
            #pragma unroll
            for (int r = 0; r < NREL; ++r) tot += deg[r * N + idx];
            cnt[idx] = tot;
            sum += tot;
        }
    }
    sdata[t] = sum; __syncthreads();
    for (int s = 128; s > 0; s >>= 1) {
        if (t < s) sdata[t] += sdata[t + s];
        __syncthreads();
    }
    if (t == 0) bsums[b] = sdata[0];
}

// single-block exclusive scan of bsums[nb], nb <= 1024
__global__ void scan_mid(int* __restrict__ bsums, int nb) {
    __shared__ int s[256];
    int t = threadIdx.x;
    int base = t * 4;
    int v[4]; int sum = 0;
    #pragma unroll
    for (int i = 0; i < 4; ++i) {
        v[i] = sum;
        int c = (base + i < nb) ? bsums[base + i] : 0;
        sum += c;
    }
    s[t] = sum; __syncthreads();
    for (int off = 1; off < 256; off <<= 1) {
        int add = (t >= off) ? s[t - off] : 0;
        __syncthreads();
        s[t] += add;
        __syncthreads();
    }
    int excl = (t == 0) ? 0 : s[t - 1];
    #pragma unroll
    for (int i = 0; i < 4; ++i)
        if (base + i < nb) bsums[base + i] = excl + v[i];
}

// rowStart[d] + packed[r*N+d] = ((rowStart[d]+prefix_r)<<11)|deg_rd
__global__ void scan_write(const int* __restrict__ cnt, const int* __restrict__ bsums,
                           const int* __restrict__ deg,
                           int* __restrict__ rowStart, unsigned* __restrict__ packed,
                           int N) {
    __shared__ int tsum[256];
    int b = blockIdx.x, t = threadIdx.x;
    int base = b * 1024 + t * 4;
    int v[4];
    int s = 0;
    #pragma unroll
    for (int i = 0; i < 4; ++i) {
        int idx = base + i;
        v[i] = s;
        int c = (idx < N) ? cnt[idx] : 0;
        s += c;
    }
    tsum[t] = s; __syncthreads();
    for (int off = 1; off < 256; off <<= 1) {
        int x = 0;
        if (t >= off) x = tsum[t - off];
        __syncthreads();
        if (t >= off) tsum[t] += x;
        __syncthreads();
    }
    int excl = (t == 0) ? 0 : tsum[t - 1];
    int boff = bsums[b];
    #pragma unroll
    for (int i = 0; i < 4; ++i) {
        int idx = base + i;
        if (idx < N) {
            int rs = boff + excl + v[i];
            rowStart[idx] = rs;
            int pre = 0;
            #pragma unroll
            for (int r = 0; r < NREL; ++r) {
                int dv = deg[r * N + idx];
                packed[r * N + idx] = ((unsigned)(rs + pre) << 11) | (unsigned)dv;
                pre += dv;
            }
        }
    }
}

// Atomic-free placement: pos = (packed>>11) + rank. ONE random read per edge.
__global__ void fill_kernel(const int* __restrict__ src, const int* __restrict__ dst,
                            const float* __restrict__ coeff,
                            const ushort* __restrict__ rank,
                            const unsigned* __restrict__ packed,
                            uint2* __restrict__ recs, int RE, int E, int N) {
    int idx = blockIdx.x * blockDim.x + threadIdx.x;
    if (idx >= RE) return;
    int r = idx / E;
    int d = dst[idx];
    unsigned p = packed[r * N + d];
    int pos = (int)(p >> 11) + (int)rank[idx];
    float inv = 1.0f / (float)(p & 2047u);
    __half2 hc = __floats2half2_rn(coeff[2 * r] * inv, coeff[2 * r + 1] * inv);
    uint2 rec;
    rec.x = (unsigned)src[idx];
    rec.y = *(unsigned*)&hc;
    recs[pos] = rec;
}

// ---------------------------------------------------------------------------
// FUSED gather + GEMM. Block = 32 dst nodes (row0..row0+31), LDS 16.9KB.
// Phase 1: wave w gathers nodes {w, w+4, ...} (8 each) into LDS agg rows
//   (half-wave per edge, 4-pair unroll, f32x2 pk-fma).
// Phase 2: out[32,128] = relu([aggLDS|xb][32,384] @ w2T^T + bias).
//   A frags: kt 0,1 from LDS; kt 2 from xb. B frags: regs from L2-hot w2T.
// ---------------------------------------------------------------------------
__global__ __launch_bounds__(256, 6) void gather_gemm(
    const uint2* __restrict__ recs, const int* __restrict__ rowStart,
    const int* __restrict__ cnt, const ushort* __restrict__ xb,
    const ushort* __restrict__ w2T, const float* __restrict__ bias,
    float* __restrict__ out, int N) {
    __shared__ __align__(16) ushort agg[32 * ALDA];   // 16.9 KB
    const int tid = threadIdx.x;
    const int wave = tid >> 6, lane = tid & 63;
    const int half = lane >> 5;
    const int h = lane & 31;
    const int row0 = blockIdx.x * 32;

    // ---- phase 1: gather ----
    for (int i = wave; i < 32; i += 4) {
        int d = row0 + i;
        if (d >= N) break;
        f32x2 A0 = {0.f, 0.f}, A1 = {0.f, 0.f};   // c0 side
        f32x2 B0 = {0.f, 0.f}, B1 = {0.f, 0.f};   // c1 side
        const int start = rowStart[d];
        const int len = cnt[d];
        int i2 = 0;
        for (; i2 + 8 <= len; i2 += 8) {
            uint2 r0 = recs[start + i2 + half];
            uint2 r1 = recs[start + i2 + 2 + half];
            uint2 r2 = recs[start + i2 + 4 + half];
            uint2 r3 = recs[start + i2 + 6 + half];
            uint2 u0 = *(const uint2*)(xb + (size_t)r0.x * DFEAT + h * 4);
            uint2 u1 = *(const uint2*)(xb + (size_t)r1.x * DFEAT + h * 4);
            uint2 u2 = *(const uint2*)(xb + (size_t)r2.x * DFEAT + h * 4);
            uint2 u3 = *(const uint2*)(xb + (size_t)r3.x * DFEAT + h * 4);
            #pragma unroll
            for (int q = 0; q < 4; ++q) {
                uint2 rr = q == 0 ? r0 : q == 1 ? r1 : q == 2 ? r2 : r3;
                uint2 uu = q == 0 ? u0 : q == 1 ? u1 : q == 2 ? u2 : u3;
                __half2 hc = *(__half2*)&rr.y;
                float c0 = __low2float(hc), c1 = __high2float(hc);
                f32x2 cc0 = {c0, c0}, cc1 = {c1, c1};
                f32x2 f01 = {bflo(uu.x), bfhi(uu.x)};
                f32x2 f23 = {bflo(uu.y), bfhi(uu.y)};
                A0 += cc0 * f01; A1 += cc0 * f23;
                B0 += cc1 * f01; B1 += cc1 * f23;
            }
        }
        for (; i2 < len; i2 += 2) {
            int e = i2 + half;
            bool valid = e < len;
            uint2 rr = recs[start + (valid ? e : i2)];
            __half2 hc = *(__half2*)&rr.y;
            float c0 = valid ? __low2float(hc) : 0.f;
            float c1 = valid ? __high2float(hc) : 0.f;
            uint2 uu = *(const uint2*)(xb + (size_t)rr.x * DFEAT + h * 4);
            f32x2 cc0 = {c0, c0}, cc1 = {c1, c1};
            f32x2 f01 = {bflo(uu.x), bfhi(uu.x)};
            f32x2 f23 = {bflo(uu.y), bfhi(uu.y)};
            A0 += cc0 * f01; A1 += cc0 * f23;
            B0 += cc1 * f01; B1 += cc1 * f23;
        }
        A0.x += __shfl_xor(A0.x, 32); A0.y += __shfl_xor(A0.y, 32);
        A1.x += __shfl_xor(A1.x, 32); A1.y += __shfl_xor(A1.y, 32);
        B0.x += __shfl_xor(B0.x, 32); B0.y += __shfl_xor(B0.y, 32);
        B1.x += __shfl_xor(B1.x, 32); B1.y += __shfl_xor(B1.y, 32);
        f32x2 O01 = half ? B0 : A0;
        f32x2 O23 = half ? B1 : A1;
        ushort4 o = make_ushort4(f2bf(O01.x), f2bf(O01.y), f2bf(O23.x), f2bf(O23.y));
        *(ushort4*)(agg + i * ALDA + lane * 4) = o;
    }
    __syncthreads();

    // ---- phase 2: GEMM (M=32) ----
    const int quad = lane >> 4, l16 = lane & 15;
    int arow[2];
    #pragma unroll
    for (int m = 0; m < 2; ++m) {
        int r = row0 + m * 16 + l16;
        arow[m] = (r < N) ? r : 0;
    }

    f32x4 zero = {0.f, 0.f, 0.f, 0.f};
    f32x4 acc[2][2] = {{zero, zero}, {zero, zero}};

    #pragma unroll
    for (int kt = 0; kt < 3; ++kt) {
        bf16x8 bq[4][2];
        #pragma unroll
        for (int t = 0; t < 4; ++t)
            #pragma unroll
            for (int g = 0; g < 2; ++g)
                bq[t][g] = *(const bf16x8*)(w2T + (size_t)(wave * 32 + g * 16 + l16) * 384
                                            + kt * 128 + t * 32 + quad * 8);
        #pragma unroll
        for (int m = 0; m < 2; ++m) {
            #pragma unroll
            for (int t = 0; t < 4; ++t) {
                bf16x8 a;
                if (kt < 2)
                    a = *(const bf16x8*)(agg + (m * 16 + l16) * ALDA + kt * 128 + t * 32 + quad * 8);
                else
                    a = *(const bf16x8*)(xb + (size_t)arow[m] * DFEAT + t * 32 + quad * 8);
                acc[m][0] = __builtin_amdgcn_mfma_f32_16x16x32_bf16(a, bq[t][0], acc[m][0], 0, 0, 0);
                acc[m][1] = __builtin_amdgcn_mfma_f32_16x16x32_bf16(a, bq[t][1], acc[m][1], 0, 0, 0);
            }
        }
    }

    #pragma unroll
    for (int g = 0; g < 2; ++g) {
        int c = wave * 32 + g * 16 + l16;
        float bv = bias[c];
        #pragma unroll
        for (int m = 0; m < 2; ++m) {
            #pragma unroll
            for (int reg = 0; reg < 4; ++reg) {
                int grow = row0 + m * 16 + quad * 4 + reg;
                if (grow < N)
                    out[(size_t)grow * DFEAT + c] = fmaxf(acc[m][g][reg] + bv, 0.f);
            }
        }
    }
}

extern "C" void kernel_launch(void* const* d_in, const int* in_sizes, int n_in,
                              void* d_out, int out_size, void* d_ws, size_t ws_size,
                              hipStream_t stream) {
    const float* x     = (const float*)d_in[0];
    const int*   src   = (const int*)  d_in[1];
    const int*   dst   = (const int*)  d_in[2];
    const float* coeff = (const float*)d_in[3];
    const float* bases = (const float*)d_in[4];
    const float* loopw = (const float*)d_in[5];
    const float* bias  = (const float*)d_in[6];
    float* out = (float*)d_out;

    const int N  = in_sizes[0] / DFEAT;            // 100000
    const int RE = in_sizes[1];                    // R*E = 1200000
    const int B  = in_sizes[4] / (DFEAT * DFEAT);  // 2
    const int R  = in_sizes[3] / B;                // 8
    const int E  = RE / R;                         // 150000
    const int NB = (N + 1023) / 1024;              // scan blocks

    // workspace layout
    char* ws = (char*)d_ws;
    size_t off = 0;
    auto alloc = [&](size_t bytes) { void* p = ws + off; off = (off + bytes + 255) & ~(size_t)255; return p; };
    int*      deg      = (int*)     alloc((size_t)R * N * sizeof(int));     // 3.2 MB
    ushort*   rank     = (ushort*)  alloc((size_t)RE * sizeof(ushort));     // 2.4 MB
    unsigned* packed   = (unsigned*)alloc((size_t)R * N * sizeof(unsigned));// 3.2 MB
    int*      cnt      = (int*)     alloc((size_t)N * sizeof(int));
    int*      rowStart = (int*)     alloc((size_t)N * sizeof(int));
    int*      bsums    = (int*)     alloc((size_t)NB * sizeof(int));
    ushort*   w2T      = (ushort*)  alloc((size_t)128 * 384 * sizeof(ushort));
    ushort*   xb       = (ushort*)  alloc((size_t)N * DFEAT * sizeof(ushort)); // 25.6 MB
    uint2*    recs     = (uint2*)   alloc((size_t)RE * sizeof(uint2));         // 9.6 MB

    hipMemsetAsync(deg, 0, (size_t)R * N * sizeof(int), stream);
    fused_pre<<<4096, 256, 0, stream>>>(dst, deg, rank, x, xb, bases, loopw, w2T,
                                        RE, E, N, N * 32);
    scan_block_sums<<<NB, 256, 0, stream>>>(deg, cnt, bsums, N);
    scan_mid<<<1, 256, 0, stream>>>(bsums, NB);
    scan_write<<<NB, 256, 0, stream>>>(cnt, bsums, deg, rowStart, packed, N);
    fill_kernel<<<(RE + 255) / 256, 256, 0, stream>>>(src, dst, coeff, rank, packed,
                                                      recs, RE, E, N);

    gather_gemm<<<(N + 31) / 32, 256, 0, stream>>>(recs, rowStart, cnt, xb, w2T,
                                                   bias, out, N);
}